// Round 2
// baseline (1105.734 us; speedup 1.0000x reference)
//
#include <hip/hip_runtime.h>
#include <hip/hip_bf16.h>
#include <math.h>

#define DEVI __device__ __forceinline__

constexpr int BATCH = 4;
constexpr int LTOT  = 5376;   // 4096 + 1024 + 256
constexpr int NINST = 100;
constexpr int NCLS  = 80;
constexpr int KPAR  = 169;

DEVI float waveAllSum(float v) {
#pragma unroll
  for (int s = 32; s > 0; s >>= 1) v += __shfl_xor(v, s, 64);
  return v;
}
DEVI float siluf(float x) { return x / (1.0f + expf(-x)); }
DEVI float sigmf(float x) { return 1.0f / (1.0f + expf(-x)); }

// ---------------- fused Linear(C=256->256) + LayerNorm + SiLU ----------------
// 16 rows / block, 256 threads. wave rg owns rows 4rg..4rg+3 fully (LN via shfl).
// Safe for in == out (block reads only its own rows, fully staged before writes).
__global__ __launch_bounds__(256) void mlp_layer(
    const float* __restrict__ in, float* __restrict__ out,
    const float* __restrict__ w, const float* __restrict__ hb,
    const float* __restrict__ g, const float* __restrict__ lb)
{
  __shared__ float xs[256][17];     // [k][row], pad 17 to break bank conflicts
  __shared__ float wsm[32][256];    // k-block of W, [kk][o]
  const int tid = threadIdx.x;
  const int rg = tid >> 6, cg = tid & 63;
  const long r0 = (long)blockIdx.x * 16;
  {
    const int i = tid >> 4, kq = tid & 15;
    const float4* src = reinterpret_cast<const float4*>(in + (r0 + i) * 256);
#pragma unroll
    for (int qq = 0; qq < 4; ++qq) {
      const int k4 = kq + 16 * qq;
      float4 v = src[k4];
      xs[4*k4+0][i] = v.x; xs[4*k4+1][i] = v.y;
      xs[4*k4+2][i] = v.z; xs[4*k4+3][i] = v.w;
    }
  }
  float acc[4][4] = {};
  for (int kb = 0; kb < 8; ++kb) {
    __syncthreads();
#pragma unroll
    for (int kk = 0; kk < 32; ++kk) wsm[kk][tid] = w[(kb*32 + kk)*256 + tid];
    __syncthreads();
#pragma unroll
    for (int kk = 0; kk < 32; ++kk) {
      const float4 wv = *reinterpret_cast<const float4*>(&wsm[kk][4*cg]);
#pragma unroll
      for (int i = 0; i < 4; ++i) {
        const float a = xs[kb*32+kk][4*rg+i];
        acc[i][0] += a*wv.x; acc[i][1] += a*wv.y;
        acc[i][2] += a*wv.z; acc[i][3] += a*wv.w;
      }
    }
  }
  const float4 hb4 = *reinterpret_cast<const float4*>(&hb[4*cg]);
  const float4 g4  = *reinterpret_cast<const float4*>(&g[4*cg]);
  const float4 lb4 = *reinterpret_cast<const float4*>(&lb[4*cg]);
#pragma unroll
  for (int i = 0; i < 4; ++i) {
    float y0 = acc[i][0]+hb4.x, y1 = acc[i][1]+hb4.y;
    float y2 = acc[i][2]+hb4.z, y3 = acc[i][3]+hb4.w;
    const float m = waveAllSum(y0+y1+y2+y3) * (1.0f/256.0f);
    const float d0=y0-m, d1=y1-m, d2=y2-m, d3=y3-m;
    const float var = waveAllSum(d0*d0+d1*d1+d2*d2+d3*d3) * (1.0f/256.0f);
    const float rs = rsqrtf(var + 1e-5f);
    float4 ov = { siluf(g4.x*d0*rs + lb4.x), siluf(g4.y*d1*rs + lb4.y),
                  siluf(g4.z*d2*rs + lb4.z), siluf(g4.w*d3*rs + lb4.w) };
    *reinterpret_cast<float4*>(&out[(r0 + 4*rg + i)*256 + 4*cg]) = ov;
  }
}

// ---------------- 1x1 conv + BN affine (lateral). out[o,p] = s[o]*sum_c x[c,p]w[o,c] + b[o]
// TRANS=true  -> writes flat[(b*L + baseL + p)*256 + o]
// TRANS=false -> writes out[(b*256 + o)*P + p]
template<bool TRANS>
__global__ __launch_bounds__(256) void lateral(
    const float* __restrict__ x, const float* __restrict__ w,
    const float* __restrict__ sc, const float* __restrict__ bi,
    float* __restrict__ out, int K, int P, int baseL)
{
  __shared__ float xs[32][17];
  __shared__ float wsm[32][256];
  const int tid = threadIdx.x;
  const int rg = tid >> 6, cg = tid & 63;
  const int tilesPerB = P >> 4;
  const int b  = blockIdx.x / tilesPerB;
  const int p0 = (blockIdx.x % tilesPerB) << 4;
  const float* xb = x + (long)b * K * P;
  float acc[4][4] = {};
  const int nkb = K >> 5;
  for (int kb = 0; kb < nkb; ++kb) {
    __syncthreads();
    {
      const int kk = tid >> 4, i = tid & 15;
      xs[kk][i]    = xb[(long)(kb*32 + kk)*P + p0 + i];
      xs[kk+16][i] = xb[(long)(kb*32 + kk + 16)*P + p0 + i];
    }
    {
      const float4* wr = reinterpret_cast<const float4*>(w + (long)tid*K + kb*32);
#pragma unroll
      for (int kq = 0; kq < 8; ++kq) {
        float4 v = wr[kq];
        wsm[4*kq+0][tid]=v.x; wsm[4*kq+1][tid]=v.y;
        wsm[4*kq+2][tid]=v.z; wsm[4*kq+3][tid]=v.w;
      }
    }
    __syncthreads();
#pragma unroll
    for (int kk = 0; kk < 32; ++kk) {
      const float4 wv = *reinterpret_cast<const float4*>(&wsm[kk][4*cg]);
#pragma unroll
      for (int i = 0; i < 4; ++i) {
        const float a = xs[kk][4*rg+i];
        acc[i][0]+=a*wv.x; acc[i][1]+=a*wv.y; acc[i][2]+=a*wv.z; acc[i][3]+=a*wv.w;
      }
    }
  }
  const float4 s4 = *reinterpret_cast<const float4*>(&sc[4*cg]);
  const float4 b4 = *reinterpret_cast<const float4*>(&bi[4*cg]);
  if (TRANS) {
#pragma unroll
    for (int i = 0; i < 4; ++i) {
      float4 ov = { acc[i][0]*s4.x+b4.x, acc[i][1]*s4.y+b4.y,
                    acc[i][2]*s4.z+b4.z, acc[i][3]*s4.w+b4.w };
      *reinterpret_cast<float4*>(&out[((long)b*LTOT + baseL + p0 + 4*rg + i)*256 + 4*cg]) = ov;
    }
  } else {
    const float ss[4] = {s4.x, s4.y, s4.z, s4.w};
    const float bb[4] = {b4.x, b4.y, b4.z, b4.w};
#pragma unroll
    for (int j = 0; j < 4; ++j) {
      float4 ov = { acc[0][j]*ss[j]+bb[j], acc[1][j]*ss[j]+bb[j],
                    acc[2][j]*ss[j]+bb[j], acc[3][j]*ss[j]+bb[j] };
      *reinterpret_cast<float4*>(&out[((long)b*256 + 4*cg + j)*(long)P + p0 + 4*rg]) = ov;
    }
  }
}

// ---------------- loc final Linear 256->1 (+bias) ----------------
__global__ __launch_bounds__(256) void loc_final(
    const float* __restrict__ h, const float* __restrict__ fw,
    const float* __restrict__ fb, float* __restrict__ logits)
{
  const int row = blockIdx.x*4 + (threadIdx.x >> 6);
  const int lane = threadIdx.x & 63;
  const float* xr = h + (long)row*256;
  float a = 0.f;
#pragma unroll
  for (int q = 0; q < 4; ++q) a += xr[lane + 64*q] * fw[lane + 64*q];
  a = waveAllSum(a);
  if (lane == 0) logits[row] = a + fb[0];
}

// ---------------- exact stable top-100 + scores + count + gfeat gather ----------------
__global__ __launch_bounds__(256) void topk_gather(
    const float* __restrict__ logits, const float* __restrict__ flat,
    int* __restrict__ topi, float* __restrict__ gfeat,
    float* __restrict__ dout)
{
  __shared__ float sv[LTOT];
  __shared__ float rv[4];
  __shared__ int   ri[4];
  __shared__ int   sidx[NINST];
  const int b = blockIdx.x, tid = threadIdx.x;
  for (int l = tid; l < LTOT; l += 256) sv[l] = logits[b*LTOT + l];
  __syncthreads();
  int cnt = 0;
  for (int t = 0; t < NINST; ++t) {
    float bv = -INFINITY; int bidx = 0x7fffffff;
    for (int l = tid; l < LTOT; l += 256) {
      const float v = sv[l];
      if (v > bv) { bv = v; bidx = l; }   // ascending scan keeps smallest idx on ties
    }
#pragma unroll
    for (int s = 32; s > 0; s >>= 1) {
      const float v2 = __shfl_xor(bv, s, 64);
      const int   i2 = __shfl_xor(bidx, s, 64);
      if (v2 > bv || (v2 == bv && i2 < bidx)) { bv = v2; bidx = i2; }
    }
    if ((tid & 63) == 0) { rv[tid >> 6] = bv; ri[tid >> 6] = bidx; }
    __syncthreads();
    if (tid == 0) {
      bv = rv[0]; bidx = ri[0];
#pragma unroll
      for (int q = 1; q < 4; ++q)
        if (rv[q] > bv || (rv[q] == bv && ri[q] < bidx)) { bv = rv[q]; bidx = ri[q]; }
      sidx[t] = bidx; topi[b*NINST + t] = bidx;
      dout[4 + b*NINST + t] = sigmf(bv);
      if (bv > 0.0f) ++cnt;
      sv[bidx] = -INFINITY;
    }
    __syncthreads();
  }
  if (tid == 0) dout[b] = (float)cnt;
  for (int t = 0; t < NINST; ++t) {
    const int ix = sidx[t];
    gfeat[((long)b*NINST + t)*256 + tid] = flat[((long)b*LTOT + ix)*256 + tid];
  }
}

// ---------------- cls final 256->80 + argmax ----------------
__global__ __launch_bounds__(256) void cls_head(
    const float* __restrict__ h, const float* __restrict__ fw,
    const float* __restrict__ fb, float* __restrict__ dout)
{
  __shared__ float xr[256];
  __shared__ float lv[NCLS];
  const int row = blockIdx.x, tid = threadIdx.x;
  xr[tid] = h[(long)row*256 + tid];
  __syncthreads();
  if (tid < NCLS) {
    float a = fb[tid];
    for (int k = 0; k < 256; ++k) a += xr[k]*fw[k*NCLS + tid];
    lv[tid] = a;
  }
  __syncthreads();
  if (tid == 0) {
    float bv = lv[0]; int bi2 = 0;
    for (int o = 1; o < NCLS; ++o) if (lv[o] > bv) { bv = lv[o]; bi2 = o; }
    dout[404 + row] = (float)bi2;
  }
}

// ---------------- ker final 256->169 ----------------
__global__ __launch_bounds__(256) void ker_head(
    const float* __restrict__ h, const float* __restrict__ fw,
    const float* __restrict__ fb, float* __restrict__ dyn)
{
  __shared__ float xr[256];
  const int row = blockIdx.x, tid = threadIdx.x;
  xr[tid] = h[(long)row*256 + tid];
  __syncthreads();
  if (tid < KPAR) {
    float a = fb[tid];
    for (int k = 0; k < 256; ++k) a += xr[k]*fw[k*KPAR + tid];
    dyn[(long)row*KPAR + tid] = a;
  }
}

// ---------------- 3x3 conv (SAME, zero pad), c-chunked partials ----------------
__global__ __launch_bounds__(256) void conv3(
    const float* __restrict__ mlat, const float* __restrict__ mw,
    float* __restrict__ partial)
{
  const int bid = blockIdx.x;           // [b(4)][tile(16)][cc(4)]
  const int cc = bid & 3;
  const int tile = (bid >> 2) & 15;
  const int b = bid >> 6;
  const int y0 = (tile >> 2)*16, x0 = (tile & 3)*16;
  const int tid = threadIdx.x;
  const int ly = tid >> 4, lx = tid & 15;
  __shared__ float til[18][19];
  __shared__ float wch[72];
  float acc[8] = {};
  for (int c = cc*64; c < cc*64 + 64; ++c) {
    __syncthreads();
    for (int e = tid; e < 324; e += 256) {
      const int iy = e / 18, ix = e % 18;
      const int gy = y0 - 1 + iy, gx = x0 - 1 + ix;
      float v = 0.0f;
      if (gy >= 0 && gy < 64 && gx >= 0 && gx < 64)
        v = mlat[((long)b*256 + c)*4096 + gy*64 + gx];
      til[iy][ix] = v;
    }
    if (tid < 72) wch[tid] = mw[((tid/9)*256 + c)*9 + tid % 9];
    __syncthreads();
    float t[9];
#pragma unroll
    for (int dy = 0; dy < 3; ++dy)
#pragma unroll
      for (int dx = 0; dx < 3; ++dx) t[dy*3+dx] = til[ly+dy][lx+dx];
#pragma unroll
    for (int o = 0; o < 8; ++o) {
      float a = 0.f;
#pragma unroll
      for (int q = 0; q < 9; ++q) a += t[q]*wch[o*9+q];
      acc[o] += a;
    }
  }
  const long pbase = (((long)b*4 + cc)*8)*4096 + (y0+ly)*64 + (x0+lx);
#pragma unroll
  for (int o = 0; o < 8; ++o) partial[pbase + (long)o*4096] = acc[o];
}

// ---------------- reduce conv partials + affine + SiLU ----------------
__global__ __launch_bounds__(256) void mhead_fin(
    const float* __restrict__ partial, const float* __restrict__ s,
    const float* __restrict__ bi, float* __restrict__ mhead)
{
  const int idx = blockIdx.x*256 + threadIdx.x;   // = (b*8+o)*4096+p
  const int p = idx & 4095;
  const int o = (idx >> 12) & 7;
  const int b = idx >> 15;
  float v = 0.f;
#pragma unroll
  for (int cc = 0; cc < 4; ++cc) v += partial[(((long)b*4 + cc)*8 + o)*4096 + p];
  v = v*s[o] + bi[o];
  mhead[idx] = siluf(v);
}

// ---------------- per-instance dynamic conv -> sigmoid mask 64x64 ----------------
__global__ __launch_bounds__(256) void dyn_mask(
    const float* __restrict__ dyn, const int* __restrict__ topi,
    const float* __restrict__ mhead, float* __restrict__ mask64)
{
  __shared__ float dd[KPAR];
  __shared__ float soff[2];
  const int inst = blockIdx.x, tid = threadIdx.x;
  if (tid < KPAR) dd[tid] = dyn[(long)inst*KPAR + tid];
  if (tid == 0) {
    const int l = topi[inst];
    float ox, oy;
    if (l < 4096)      { ox = ((l & 63) + 0.5f)*(1.f/64.f); oy = ((l >> 6) + 0.5f)*(1.f/64.f); }
    else if (l < 5120) { const int t = l - 4096; ox = ((t & 31) + 0.5f)*(1.f/32.f); oy = ((t >> 5) + 0.5f)*(1.f/32.f); }
    else               { const int t = l - 5120; ox = ((t & 15) + 0.5f)*(1.f/16.f); oy = ((t >> 4) + 0.5f)*(1.f/16.f); }
    soff[0] = ox; soff[1] = oy;
  }
  __syncthreads();
  const float ox = soff[0], oy = soff[1];
  const int b = inst / NINST;
  const float* mh = mhead + (long)b*8*4096;
  for (int p = tid; p < 4096; p += 256) {
    float f[10];
#pragma unroll
    for (int c = 0; c < 8; ++c) f[c] = mh[c*4096 + p];
    f[8] = ((p & 63) + 0.5f)*(1.f/64.f) - ox;
    f[9] = ((p >> 6) + 0.5f)*(1.f/64.f) - oy;
    float m1[8];
#pragma unroll
    for (int d = 0; d < 8; ++d) {
      float t = dd[80 + d];
#pragma unroll
      for (int c = 0; c < 10; ++c) t += f[c]*dd[c*8 + d];
      m1[d] = siluf(t);
    }
    float m2[8];
#pragma unroll
    for (int d = 0; d < 8; ++d) {
      float t = dd[152 + d];
#pragma unroll
      for (int c = 0; c < 8; ++c) t += m1[c]*dd[88 + c*8 + d];
      m2[d] = siluf(t);
    }
    float o = dd[168];
#pragma unroll
    for (int c = 0; c < 8; ++c) o += m2[c]*dd[160 + c];
    mask64[(long)inst*4096 + p] = sigmf(o);
  }
}

// ---------------- bilinear 8x upsample 64->512 (jax.image.resize semantics) ----------------
__global__ __launch_bounds__(256) void resize_k(
    const float* __restrict__ m64, float* __restrict__ dout)
{
  const long gid = (long)blockIdx.x*256 + threadIdx.x;   // inst*512*64 + y*64 + j
  const int j = (int)(gid & 63);
  const long r = gid >> 6;
  const int y = (int)(r & 511);
  const int inst = (int)(r >> 9);
  const float* src = m64 + (long)inst*4096;
  const float ty = (y + 0.5f)*0.125f - 0.5f;
  const float fyf = floorf(ty);
  const int iy0 = (int)fyf;
  const float fy = ty - fyf;
  const int y0c = iy0 < 0 ? 0 : iy0;
  const int y1c = (iy0 + 1 > 63) ? 63 : iy0 + 1;
  const int xm = j > 0 ? j - 1 : 0;
  const int xp = j < 63 ? j + 1 : 63;
  const float* r0p = src + y0c*64;
  const float* r1p = src + y1c*64;
  const float w1 = fy, w0 = 1.0f - fy;
  const float va = r0p[xm]*w0 + r1p[xm]*w1;
  const float vb = r0p[j]*w0  + r1p[j]*w1;
  const float vc = r0p[xp]*w0 + r1p[xp]*w1;
  float4 o0, o1;
  {
    float fx0 = 0.5625f, fx1 = 0.6875f, fx2 = 0.8125f, fx3 = 0.9375f;
    o0.x = va + (vb - va)*fx0; o0.y = va + (vb - va)*fx1;
    o0.z = va + (vb - va)*fx2; o0.w = va + (vb - va)*fx3;
  }
  {
    float fx0 = 0.0625f, fx1 = 0.1875f, fx2 = 0.3125f, fx3 = 0.4375f;
    o1.x = vb + (vc - vb)*fx0; o1.y = vb + (vc - vb)*fx1;
    o1.z = vb + (vc - vb)*fx2; o1.w = vb + (vc - vb)*fx3;
  }
  float* dst = dout + 804 + ((long)inst << 18) + ((long)y << 9) + (j << 3);
  *reinterpret_cast<float4*>(dst) = o0;       // element offset 804 is 16B-aligned
  *reinterpret_cast<float4*>(dst + 4) = o1;
}

extern "C" void kernel_launch(void* const* d_in, const int* in_sizes, int n_in,
                              void* d_out, int out_size, void* d_ws, size_t ws_size,
                              hipStream_t stream)
{
  (void)in_sizes; (void)n_in; (void)out_size; (void)ws_size;
  const float* x3      = (const float*)d_in[3];
  const float* x4      = (const float*)d_in[4];
  const float* x5      = (const float*)d_in[5];
  const float* lat3_w  = (const float*)d_in[6];
  const float* lat3_s  = (const float*)d_in[7];
  const float* lat3_b  = (const float*)d_in[8];
  const float* lat4_w  = (const float*)d_in[9];
  const float* lat4_s  = (const float*)d_in[10];
  const float* lat4_b  = (const float*)d_in[11];
  const float* lat5_w  = (const float*)d_in[12];
  const float* lat5_s  = (const float*)d_in[13];
  const float* lat5_b  = (const float*)d_in[14];
  const float* mlat_w  = (const float*)d_in[15];
  const float* mlat_s  = (const float*)d_in[16];
  const float* mlat_b  = (const float*)d_in[17];
  const float* mhead_w = (const float*)d_in[18];
  const float* mhead_s = (const float*)d_in[19];
  const float* mhead_b = (const float*)d_in[20];
  const float* loc_hw  = (const float*)d_in[21];
  const float* loc_hb  = (const float*)d_in[22];
  const float* loc_lng = (const float*)d_in[23];
  const float* loc_lnb = (const float*)d_in[24];
  const float* loc_fw  = (const float*)d_in[25];
  const float* loc_fb  = (const float*)d_in[26];
  const float* cls_hw  = (const float*)d_in[27];
  const float* cls_hb  = (const float*)d_in[28];
  const float* cls_lng = (const float*)d_in[29];
  const float* cls_lnb = (const float*)d_in[30];
  const float* cls_fw  = (const float*)d_in[31];
  const float* cls_fb  = (const float*)d_in[32];
  const float* ker_hw  = (const float*)d_in[33];
  const float* ker_hb  = (const float*)d_in[34];
  const float* ker_lng = (const float*)d_in[35];
  const float* ker_lnb = (const float*)d_in[36];
  const float* ker_fw  = (const float*)d_in[37];
  const float* ker_fb  = (const float*)d_in[38];

  // workspace layout (floats). Total 12,840,352 floats = 51.4 MB.
  float* ws      = (float*)d_ws;
  float* flat    = ws;                      // [4][5376][256] = 5,505,024
  float* buf     = ws + 5505024;            // 5,505,024 (loc MLP hidden; later reused)
  float* mlatb   = buf;                     //   [4][256][4096] = 4,194,304
  float* partial = buf + 4194304;           //   [4][4][8][4096] = 524,288
  float* mheadb  = buf + 4718592;           //   [4][8][4096]    = 131,072
  float* h1      = buf + 4849664;           //   [400][256]      = 102,400
  float* logits  = ws + 11010048;           // [4][5376] = 21,504
  int*   topi    = (int*)(ws + 11031552);   // [4][100]
  float* gfeat   = ws + 11031952;           // [400][256] = 102,400
  float* dynb    = ws + 11134352;           // [400][169] = 67,600
  float* mask64  = ws + 11201952;           // [400][4096] = 1,638,400
  float* dout    = (float*)d_out;

  // laterals -> flat [b, l, c]
  lateral<true><<<1024, 256, 0, stream>>>(x3, lat3_w, lat3_s, lat3_b, flat, 256, 4096, 0);
  lateral<true><<<256,  256, 0, stream>>>(x4, lat4_w, lat4_s, lat4_b, flat, 512, 1024, 4096);
  lateral<true><<<64,   256, 0, stream>>>(x5, lat5_w, lat5_s, lat5_b, flat, 1024, 256, 5120);

  // loc MLP (21504 rows)
  for (int i = 0; i < 4; ++i)
    mlp_layer<<<1344, 256, 0, stream>>>(i == 0 ? flat : buf, buf,
        loc_hw + i*65536, loc_hb + i*256, loc_lng + i*256, loc_lnb + i*256);
  loc_final<<<5376, 256, 0, stream>>>(buf, loc_fw, loc_fb, logits);
  topk_gather<<<4, 256, 0, stream>>>(logits, flat, topi, gfeat, dout);

  // cls MLP (400 rows) + argmax
  for (int i = 0; i < 4; ++i)
    mlp_layer<<<25, 256, 0, stream>>>(i == 0 ? gfeat : h1, h1,
        cls_hw + i*65536, cls_hb + i*256, cls_lng + i*256, cls_lnb + i*256);
  cls_head<<<400, 256, 0, stream>>>(h1, cls_fw, cls_fb, dout);

  // ker MLP (400 rows) -> dynamic kernel params
  for (int i = 0; i < 4; ++i)
    mlp_layer<<<25, 256, 0, stream>>>(i == 0 ? gfeat : h1, h1,
        ker_hw + i*65536, ker_hb + i*256, ker_lng + i*256, ker_lnb + i*256);
  ker_head<<<400, 256, 0, stream>>>(h1, ker_fw, ker_fb, dynb);

  // mask branch
  lateral<false><<<1024, 256, 0, stream>>>(x3, mlat_w, mlat_s, mlat_b, mlatb, 256, 4096, 0);
  conv3<<<256, 256, 0, stream>>>(mlatb, mhead_w, partial);
  mhead_fin<<<512, 256, 0, stream>>>(partial, mhead_s, mhead_b, mheadb);
  dyn_mask<<<400, 256, 0, stream>>>(dynb, topi, mheadb, mask64);
  resize_k<<<51200, 256, 0, stream>>>(mask64, dout);
}

// Round 3
// 864.134 us; speedup vs baseline: 1.2796x; 1.2796x over previous
//
#include <hip/hip_runtime.h>
#include <hip/hip_bf16.h>
#include <math.h>

#define DEVI __device__ __forceinline__

constexpr int LTOT  = 5376;   // 4096 + 1024 + 256
constexpr int NINST = 100;
constexpr int NCLS  = 80;
constexpr int KPAR  = 169;

DEVI float waveAllSum(float v) {
#pragma unroll
  for (int s = 32; s > 0; s >>= 1) v += __shfl_xor(v, s, 64);
  return v;
}
DEVI float siluf(float x) { return x / (1.0f + expf(-x)); }
DEVI float sigmf(float x) { return 1.0f / (1.0f + expf(-x)); }

// ---------------- fused Linear(256->256) + LayerNorm + SiLU ----------------
// MODE 0: write LN+SiLU rows to out.
// MODE 1: additionally dot with fw (256->1) and write logits only (no out write).
// MODE 2: dual weight sets: blocks >= gridDim/2 use set-1 weights; input row
//         offset by rowDelta for set-1 blocks (layer 1 reads gfeat twice).
template<int MODE>
__global__ __launch_bounds__(256) void mlp_layer(
    const float* __restrict__ in, float* __restrict__ out,
    const float* __restrict__ w0, const float* __restrict__ hb0,
    const float* __restrict__ g0, const float* __restrict__ lb0,
    const float* __restrict__ w1, const float* __restrict__ hb1,
    const float* __restrict__ g1, const float* __restrict__ lb1,
    const float* __restrict__ fw, const float* __restrict__ fb,
    float* __restrict__ logits, int rowDelta)
{
  __shared__ float xs[256][20];   // [k][row], stride 20 -> 16B-aligned b128 broadcasts
  __shared__ float wsm[32][256];  // k-block of W, [kk][o]
  const int tid = threadIdx.x;
  const int rg = tid >> 6, cg = tid & 63;
  const long r0 = (long)blockIdx.x * 16;
  bool set1 = false;
  const float *w = w0, *hb = hb0, *g = g0, *lb = lb0;
  if (MODE == 2) {
    set1 = (blockIdx.x >= (gridDim.x >> 1));
    if (set1) { w = w1; hb = hb1; g = g1; lb = lb1; }
  }
  const long ir0 = r0 + ((MODE == 2 && set1) ? rowDelta : 0);
  {
    const int i = tid >> 4, kq = tid & 15;
    const float4* src = reinterpret_cast<const float4*>(in + (ir0 + i) * 256);
#pragma unroll
    for (int qq = 0; qq < 4; ++qq) {
      const int k4 = kq + 16 * qq;
      const float4 v = src[k4];
      xs[4*k4+0][i] = v.x; xs[4*k4+1][i] = v.y;
      xs[4*k4+2][i] = v.z; xs[4*k4+3][i] = v.w;
    }
  }
  float acc[4][4] = {};
  for (int kb = 0; kb < 8; ++kb) {
    __syncthreads();
    {
      const float4* w4 = reinterpret_cast<const float4*>(w + kb*32*256);
#pragma unroll
      for (int qb = 0; qb < 8; ++qb) {
        const int c = tid + 256*qb;            // float4 index in 32x256 chunk
        const float4 f = w4[c];                // coalesced b128
        *reinterpret_cast<float4*>(&wsm[c>>6][4*(c&63)]) = f;  // conflict-free b128
      }
    }
    __syncthreads();
#pragma unroll
    for (int kk = 0; kk < 32; ++kk) {
      const float4 wv = *reinterpret_cast<const float4*>(&wsm[kk][4*cg]);
      const float4 av = *reinterpret_cast<const float4*>(&xs[kb*32+kk][4*rg]);
      const float ar[4] = {av.x, av.y, av.z, av.w};
#pragma unroll
      for (int i = 0; i < 4; ++i) {
        acc[i][0] += ar[i]*wv.x; acc[i][1] += ar[i]*wv.y;
        acc[i][2] += ar[i]*wv.z; acc[i][3] += ar[i]*wv.w;
      }
    }
  }
  const float4 hb4 = *reinterpret_cast<const float4*>(&hb[4*cg]);
  const float4 g4  = *reinterpret_cast<const float4*>(&g[4*cg]);
  const float4 lb4 = *reinterpret_cast<const float4*>(&lb[4*cg]);
  float4 fw4 = {0,0,0,0}; float fbv = 0.f;
  if (MODE == 1) { fw4 = *reinterpret_cast<const float4*>(&fw[4*cg]); fbv = fb[0]; }
#pragma unroll
  for (int i = 0; i < 4; ++i) {
    float y0 = acc[i][0]+hb4.x, y1 = acc[i][1]+hb4.y;
    float y2 = acc[i][2]+hb4.z, y3 = acc[i][3]+hb4.w;
    const float m = waveAllSum(y0+y1+y2+y3) * (1.0f/256.0f);
    const float d0=y0-m, d1=y1-m, d2=y2-m, d3=y3-m;
    const float var = waveAllSum(d0*d0+d1*d1+d2*d2+d3*d3) * (1.0f/256.0f);
    const float rs = rsqrtf(var + 1e-5f);
    const float4 ov = { siluf(g4.x*d0*rs + lb4.x), siluf(g4.y*d1*rs + lb4.y),
                        siluf(g4.z*d2*rs + lb4.z), siluf(g4.w*d3*rs + lb4.w) };
    if (MODE == 1) {
      float dot = ov.x*fw4.x + ov.y*fw4.y + ov.z*fw4.z + ov.w*fw4.w;
      dot = waveAllSum(dot);
      if (cg == 0) logits[r0 + 4*rg + i] = dot + fbv;
    } else {
      *reinterpret_cast<float4*>(&out[(r0 + 4*rg + i)*256 + 4*cg]) = ov;
    }
  }
}

// ---------------- all four 1x1 conv + BN laterals in one launch ----------------
// blocks [0,1024) lat3->flat, [1024,1280) lat4->flat, [1280,1344) lat5->flat,
// [1344,2368) mlat->mlatb (channel-major).
__global__ __launch_bounds__(256) void lateral_all(
    const float* __restrict__ x3, const float* __restrict__ x4, const float* __restrict__ x5,
    const float* __restrict__ w3, const float* __restrict__ s3, const float* __restrict__ b3,
    const float* __restrict__ w4, const float* __restrict__ s4, const float* __restrict__ b4,
    const float* __restrict__ w5, const float* __restrict__ s5, const float* __restrict__ b5,
    const float* __restrict__ wm, const float* __restrict__ sm, const float* __restrict__ bm,
    float* __restrict__ flat, float* __restrict__ mlatb)
{
  __shared__ float xs[32][20];
  __shared__ float wsm[32][256];
  const int tid = threadIdx.x;
  const int rg = tid >> 6, cg = tid & 63;
  const int bid = blockIdx.x;
  const float *x, *w, *sc, *bi; int K, P, pshift, rel, baseL; bool trans = true;
  if (bid < 1024)      { rel=bid;      x=x3; w=w3; sc=s3; bi=b3; K=256;  P=4096; pshift=8; baseL=0; }
  else if (bid < 1280) { rel=bid-1024; x=x4; w=w4; sc=s4; bi=b4; K=512;  P=1024; pshift=6; baseL=4096; }
  else if (bid < 1344) { rel=bid-1280; x=x5; w=w5; sc=s5; bi=b5; K=1024; P=256;  pshift=4; baseL=5120; }
  else                 { rel=bid-1344; x=x3; w=wm; sc=sm; bi=bm; K=256;  P=4096; pshift=8; baseL=0; trans=false; }
  const int b = rel >> pshift;
  const int p0 = (rel - (b << pshift)) << 4;
  const float* xb = x + (long)b * K * P;
  float acc[4][4] = {};
  const int nkb = K >> 5;
  for (int kb = 0; kb < nkb; ++kb) {
    __syncthreads();
    {
      const int kk = tid >> 4, i = tid & 15;
      xs[kk][i]    = xb[(long)(kb*32 + kk)*P + p0 + i];
      xs[kk+16][i] = xb[(long)(kb*32 + kk + 16)*P + p0 + i];
    }
    {
      const float4* wr = reinterpret_cast<const float4*>(w + (long)tid*K + kb*32);
#pragma unroll
      for (int kq = 0; kq < 8; ++kq) {
        const float4 v = wr[kq];
        wsm[4*kq+0][tid]=v.x; wsm[4*kq+1][tid]=v.y;
        wsm[4*kq+2][tid]=v.z; wsm[4*kq+3][tid]=v.w;
      }
    }
    __syncthreads();
#pragma unroll
    for (int kk = 0; kk < 32; ++kk) {
      const float4 wv = *reinterpret_cast<const float4*>(&wsm[kk][4*cg]);
      const float4 av = *reinterpret_cast<const float4*>(&xs[kk][4*rg]);
      const float ar[4] = {av.x, av.y, av.z, av.w};
#pragma unroll
      for (int i = 0; i < 4; ++i) {
        acc[i][0]+=ar[i]*wv.x; acc[i][1]+=ar[i]*wv.y;
        acc[i][2]+=ar[i]*wv.z; acc[i][3]+=ar[i]*wv.w;
      }
    }
  }
  const float4 s4v = *reinterpret_cast<const float4*>(&sc[4*cg]);
  const float4 b4v = *reinterpret_cast<const float4*>(&bi[4*cg]);
  if (trans) {
#pragma unroll
    for (int i = 0; i < 4; ++i) {
      const float4 ov = { acc[i][0]*s4v.x+b4v.x, acc[i][1]*s4v.y+b4v.y,
                          acc[i][2]*s4v.z+b4v.z, acc[i][3]*s4v.w+b4v.w };
      *reinterpret_cast<float4*>(&flat[((long)b*LTOT + baseL + p0 + 4*rg + i)*256 + 4*cg]) = ov;
    }
  } else {
    const float ss[4] = {s4v.x, s4v.y, s4v.z, s4v.w};
    const float bb[4] = {b4v.x, b4v.y, b4v.z, b4v.w};
#pragma unroll
    for (int j = 0; j < 4; ++j) {
      const float4 ov = { acc[0][j]*ss[j]+bb[j], acc[1][j]*ss[j]+bb[j],
                          acc[2][j]*ss[j]+bb[j], acc[3][j]*ss[j]+bb[j] };
      *reinterpret_cast<float4*>(&mlatb[((long)b*256 + 4*cg + j)*(long)P + p0 + 4*rg]) = ov;
    }
  }
}

// ---------------- exact stable top-100 + scores + count + gfeat gather ----------------
__global__ __launch_bounds__(256) void topk_gather(
    const float* __restrict__ logits, const float* __restrict__ flat,
    int* __restrict__ topi, float* __restrict__ gfeat,
    float* __restrict__ dout)
{
  __shared__ float sv[LTOT];
  __shared__ float rv[4];
  __shared__ int   ri[4];
  __shared__ int   sidx[NINST];
  const int b = blockIdx.x, tid = threadIdx.x;
  for (int l = tid; l < LTOT; l += 256) sv[l] = logits[b*LTOT + l];
  __syncthreads();
  int cnt = 0;
  for (int t = 0; t < NINST; ++t) {
    float bv = -INFINITY; int bidx = 0x7fffffff;
    for (int l = tid; l < LTOT; l += 256) {
      const float v = sv[l];
      if (v > bv) { bv = v; bidx = l; }   // ascending scan keeps smallest idx on ties
    }
#pragma unroll
    for (int s = 32; s > 0; s >>= 1) {
      const float v2 = __shfl_xor(bv, s, 64);
      const int   i2 = __shfl_xor(bidx, s, 64);
      if (v2 > bv || (v2 == bv && i2 < bidx)) { bv = v2; bidx = i2; }
    }
    if ((tid & 63) == 0) { rv[tid >> 6] = bv; ri[tid >> 6] = bidx; }
    __syncthreads();
    if (tid == 0) {
      bv = rv[0]; bidx = ri[0];
#pragma unroll
      for (int q = 1; q < 4; ++q)
        if (rv[q] > bv || (rv[q] == bv && ri[q] < bidx)) { bv = rv[q]; bidx = ri[q]; }
      sidx[t] = bidx; topi[b*NINST + t] = bidx;
      dout[4 + b*NINST + t] = sigmf(bv);
      if (bv > 0.0f) ++cnt;
      sv[bidx] = -INFINITY;
    }
    __syncthreads();
  }
  if (tid == 0) dout[b] = (float)cnt;
  for (int t = 0; t < NINST; ++t) {
    const int ix = sidx[t];
    gfeat[((long)b*NINST + t)*256 + tid] = flat[((long)b*LTOT + ix)*256 + tid];
  }
}

// ---------------- cls argmax head + ker param head (merged) ----------------
__global__ __launch_bounds__(256) void heads(
    const float* __restrict__ h2, const float* __restrict__ cfw, const float* __restrict__ cfb,
    const float* __restrict__ kfw, const float* __restrict__ kfb,
    float* __restrict__ dout, float* __restrict__ dyn)
{
  __shared__ float xr[256];
  __shared__ float lv[NCLS];
  const int bid = blockIdx.x, tid = threadIdx.x;
  xr[tid] = h2[(long)bid*256 + tid];
  __syncthreads();
  if (bid < 400) {
    if (tid < NCLS) {
      float a0=0.f, a1=0.f, a2=0.f, a3=0.f;
      for (int k = 0; k < 256; k += 4) {
        a0 += xr[k+0]*cfw[(k+0)*NCLS + tid];
        a1 += xr[k+1]*cfw[(k+1)*NCLS + tid];
        a2 += xr[k+2]*cfw[(k+2)*NCLS + tid];
        a3 += xr[k+3]*cfw[(k+3)*NCLS + tid];
      }
      lv[tid] = (a0+a1) + (a2+a3) + cfb[tid];
    }
    __syncthreads();
    if (tid == 0) {
      float bv = lv[0]; int bi2 = 0;
      for (int o = 1; o < NCLS; ++o) if (lv[o] > bv) { bv = lv[o]; bi2 = o; }
      dout[404 + bid] = (float)bi2;
    }
  } else {
    if (tid < KPAR) {
      float a0=0.f, a1=0.f, a2=0.f, a3=0.f;
      for (int k = 0; k < 256; k += 4) {
        a0 += xr[k+0]*kfw[(k+0)*KPAR + tid];
        a1 += xr[k+1]*kfw[(k+1)*KPAR + tid];
        a2 += xr[k+2]*kfw[(k+2)*KPAR + tid];
        a3 += xr[k+3]*kfw[(k+3)*KPAR + tid];
      }
      dyn[(long)(bid-400)*KPAR + tid] = (a0+a1) + (a2+a3) + kfb[tid];
    }
  }
}

// ---------------- 3x3 conv (SAME, zero pad): 32-ch chunks, partials ----------------
__global__ __launch_bounds__(256) void conv3(
    const float* __restrict__ mlat, const float* __restrict__ mw,
    float* __restrict__ partial)
{
  const int bid = blockIdx.x;          // [b(4)][tile(16)][cc(8)]
  const int cc = bid & 7;
  const int tile = (bid >> 3) & 15;
  const int b = bid >> 7;
  const int y0 = (tile >> 2)*16, x0 = (tile & 3)*16;
  const int tid = threadIdx.x;
  const int ly = tid >> 4, lx = tid & 15;
  __shared__ float til[2][18][19];
  __shared__ float wch[8][32][12];     // padded 9->12: 16B-aligned b128 broadcasts
  for (int e = tid; e < 2304; e += 256) {
    const int o = e / 288, rem = e % 288;
    const int c = rem / 9, qq = rem - c*9;
    wch[o][c][qq] = mw[((o*256) + cc*32 + c)*9 + qq];
  }
  // hoist staging coordinates (c-invariant) out of the channel loop
  int lofs[3], gofs[3], chn[3]; bool vld[3], has[3];
  float* tf = &til[0][0][0];
#pragma unroll
  for (int s = 0; s < 3; ++s) {
    const int e = tid + 256*s;
    has[s] = (e < 648);
    lofs[s] = 0; gofs[s] = 0; chn[s] = 0; vld[s] = false;
    if (has[s]) {
      const int ch = (e >= 324) ? 1 : 0;
      const int pos = e - ch*324;
      const int iy = pos / 18, ix = pos - iy*18;
      const int gy = y0 - 1 + iy, gx = x0 - 1 + ix;
      vld[s] = (gy >= 0 && gy < 64 && gx >= 0 && gx < 64);
      lofs[s] = ch*342 + iy*19 + ix;
      gofs[s] = gy*64 + gx;
      chn[s] = ch;
    }
  }
  const float* xbase = mlat + ((long)b*256 + cc*32)*4096;
  float acc[8] = {};
  for (int r = 0; r < 16; ++r) {
    __syncthreads();
#pragma unroll
    for (int s = 0; s < 3; ++s)
      if (has[s]) tf[lofs[s]] = vld[s] ? xbase[(long)(2*r + chn[s])*4096 + gofs[s]] : 0.f;
    __syncthreads();
#pragma unroll
    for (int ch = 0; ch < 2; ++ch) {
      const int c = 2*r + ch;
      float t[9];
#pragma unroll
      for (int dy = 0; dy < 3; ++dy)
#pragma unroll
        for (int dx = 0; dx < 3; ++dx) t[dy*3+dx] = til[ch][ly+dy][lx+dx];
#pragma unroll
      for (int o = 0; o < 8; ++o) {
        const float4 wa = *reinterpret_cast<const float4*>(&wch[o][c][0]);
        const float4 wb = *reinterpret_cast<const float4*>(&wch[o][c][4]);
        const float w8 = wch[o][c][8];
        acc[o] += t[0]*wa.x + t[1]*wa.y + t[2]*wa.z + t[3]*wa.w
                + t[4]*wb.x + t[5]*wb.y + t[6]*wb.z + t[7]*wb.w + t[8]*w8;
      }
    }
  }
  const long pbase = (((long)b*8 + cc)*8)*4096 + (y0+ly)*64 + (x0+lx);
#pragma unroll
  for (int o = 0; o < 8; ++o) partial[pbase + (long)o*4096] = acc[o];
}

// ---------------- reduce conv partials + affine + SiLU ----------------
__global__ __launch_bounds__(256) void mhead_fin(
    const float* __restrict__ partial, const float* __restrict__ s,
    const float* __restrict__ bi, float* __restrict__ mhead)
{
  const int idx = blockIdx.x*256 + threadIdx.x;   // = (b*8+o)*4096+p
  const int p = idx & 4095;
  const int o = (idx >> 12) & 7;
  const int b = idx >> 15;
  float v = 0.f;
#pragma unroll
  for (int cc = 0; cc < 8; ++cc) v += partial[(((long)b*8 + cc)*8 + o)*4096 + p];
  v = v*s[o] + bi[o];
  mhead[idx] = siluf(v);
}

// ---------------- fused: dynamic 3-layer conv -> sigmoid -> bilinear 8x -> d_out ----------------
// grid 1600: inst = bid>>2 (400), q = bid&3 (output row quarter, 128 rows).
// Computes the 18 needed source rows (jax resize, antialias=False, half-pixel)
// into LDS, then writes 128x512 f32 directly.
__global__ __launch_bounds__(256) void mask_fused(
    const float* __restrict__ dyn, const int* __restrict__ topi,
    const float* __restrict__ mhead, float* __restrict__ dout)
{
  __shared__ float msrc[18][64];
  __shared__ float dd[KPAR];
  __shared__ float so[2];
  const int bid = blockIdx.x;
  const int inst = bid >> 2, q = bid & 3;
  const int tid = threadIdx.x;
  if (tid < KPAR) dd[tid] = dyn[(long)inst*KPAR + tid];
  if (tid == 0) {
    const int l = topi[inst];
    float ox, oy;
    if (l < 4096)      { ox = ((l & 63) + 0.5f)*(1.f/64.f); oy = ((l >> 6) + 0.5f)*(1.f/64.f); }
    else if (l < 5120) { const int t = l - 4096; ox = ((t & 31) + 0.5f)*(1.f/32.f); oy = ((t >> 5) + 0.5f)*(1.f/32.f); }
    else               { const int t = l - 5120; ox = ((t & 15) + 0.5f)*(1.f/16.f); oy = ((t >> 4) + 0.5f)*(1.f/16.f); }
    so[0] = ox; so[1] = oy;
  }
  __syncthreads();
  const float ox = so[0], oy = so[1];
  const int b = inst / NINST;
  const float* mh = mhead + (long)b*8*4096;
  const int r0s = 16*q - 1;           // source row held in msrc[0] (pre-clamp)
  for (int e = tid; e < 1152; e += 256) {
    const int r = e >> 6, x = e & 63;
    int sy = r0s + r; sy = sy < 0 ? 0 : (sy > 63 ? 63 : sy);
    const int p = sy*64 + x;
    float f[10];
#pragma unroll
    for (int c = 0; c < 8; ++c) f[c] = mh[c*4096 + p];
    f[8] = (x + 0.5f)*(1.f/64.f) - ox;
    f[9] = (sy + 0.5f)*(1.f/64.f) - oy;
    float m1[8];
#pragma unroll
    for (int d = 0; d < 8; ++d) {
      float t = dd[80 + d];
#pragma unroll
      for (int c = 0; c < 10; ++c) t += f[c]*dd[c*8 + d];
      m1[d] = siluf(t);
    }
    float m2[8];
#pragma unroll
    for (int d = 0; d < 8; ++d) {
      float t = dd[152 + d];
#pragma unroll
      for (int c = 0; c < 8; ++c) t += m1[c]*dd[88 + c*8 + d];
      m2[d] = siluf(t);
    }
    float o = dd[168];
#pragma unroll
    for (int c = 0; c < 8; ++c) o += m2[c]*dd[160 + c];
    msrc[r][x] = sigmf(o);
  }
  __syncthreads();
  // upsample: thread handles fixed out-col block (4 px), x-side fully hoisted
  const int j4 = tid & 127;           // float4 column
  const int half = tid >> 7;          // row parity
  const int ix0 = (j4 & 1) ? (j4 >> 1) : (j4 >> 1) - 1;
  const int xlo = ix0 < 0 ? 0 : ix0;
  const int xhi = (ix0 + 1 > 63) ? 63 : ix0 + 1;
  float fx[4];
#pragma unroll
  for (int m = 0; m < 4; ++m) {
    const int x = 4*j4 + m;
    const float tx = (x + 0.5f)*0.125f - 0.5f;
    fx[m] = tx - (float)ix0;
  }
  float* dbase = dout + 804 + ((long)inst << 18);
  for (int it = 0; it < 64; ++it) {
    const int yy = 2*it + half;
    const int y = 128*q + yy;
    const float ty = (y + 0.5f)*0.125f - 0.5f;
    const float fyf = floorf(ty);
    const int iy0 = (int)fyf;
    const float fy = ty - fyf;
    const int r0 = iy0 - r0s;         // 0..16 (clamps baked into msrc fill)
    const float L0 = msrc[r0][xlo],   R0 = msrc[r0][xhi];
    const float L1 = msrc[r0+1][xlo], R1 = msrc[r0+1][xhi];
    const float L = L0 + (L1 - L0)*fy;
    const float R = R0 + (R1 - R0)*fy;
    const float4 ov = { L + (R - L)*fx[0], L + (R - L)*fx[1],
                        L + (R - L)*fx[2], L + (R - L)*fx[3] };
    *reinterpret_cast<float4*>(&dbase[((long)y << 9) + (j4 << 2)]) = ov;
  }
}

extern "C" void kernel_launch(void* const* d_in, const int* in_sizes, int n_in,
                              void* d_out, int out_size, void* d_ws, size_t ws_size,
                              hipStream_t stream)
{
  (void)in_sizes; (void)n_in; (void)out_size; (void)ws_size;
  const float* x3      = (const float*)d_in[3];
  const float* x4      = (const float*)d_in[4];
  const float* x5      = (const float*)d_in[5];
  const float* lat3_w  = (const float*)d_in[6];
  const float* lat3_s  = (const float*)d_in[7];
  const float* lat3_b  = (const float*)d_in[8];
  const float* lat4_w  = (const float*)d_in[9];
  const float* lat4_s  = (const float*)d_in[10];
  const float* lat4_b  = (const float*)d_in[11];
  const float* lat5_w  = (const float*)d_in[12];
  const float* lat5_s  = (const float*)d_in[13];
  const float* lat5_b  = (const float*)d_in[14];
  const float* mlat_w  = (const float*)d_in[15];
  const float* mlat_s  = (const float*)d_in[16];
  const float* mlat_b  = (const float*)d_in[17];
  const float* mhead_w = (const float*)d_in[18];
  const float* mhead_s = (const float*)d_in[19];
  const float* mhead_b = (const float*)d_in[20];
  const float* loc_hw  = (const float*)d_in[21];
  const float* loc_hb  = (const float*)d_in[22];
  const float* loc_lng = (const float*)d_in[23];
  const float* loc_lnb = (const float*)d_in[24];
  const float* loc_fw  = (const float*)d_in[25];
  const float* loc_fb  = (const float*)d_in[26];
  const float* cls_hw  = (const float*)d_in[27];
  const float* cls_hb  = (const float*)d_in[28];
  const float* cls_lng = (const float*)d_in[29];
  const float* cls_lnb = (const float*)d_in[30];
  const float* cls_fw  = (const float*)d_in[31];
  const float* cls_fb  = (const float*)d_in[32];
  const float* ker_hw  = (const float*)d_in[33];
  const float* ker_hb  = (const float*)d_in[34];
  const float* ker_lng = (const float*)d_in[35];
  const float* ker_lnb = (const float*)d_in[36];
  const float* ker_fw  = (const float*)d_in[37];
  const float* ker_fb  = (const float*)d_in[38];

  // workspace layout (floats), non-overlapping, total ~16.8M floats = 67 MB
  float* ws      = (float*)d_ws;
  float* flat    = ws;                       // [4][5376][256] = 5,505,024
  float* buf     = ws + 5505024;             // [4][5376][256] loc hidden
  float* mlatb   = ws + 11010048;            // [4][256][4096] = 4,194,304
  float* partial = ws + 15204352;            // [4][8][8][4096] = 1,048,576
  float* mheadb  = ws + 16252928;            // [4][8][4096] = 131,072
  float* h2      = ws + 16384000;            // [800][256] = 204,800
  float* logits  = ws + 16588800;            // [4][5376] = 21,504
  int*   topi    = (int*)(ws + 16610304);    // [400]
  float* gfeat   = ws + 16610704;            // [400][256] = 102,400
  float* dynb    = ws + 16713104;            // [400][169] = 67,600
  float* dout    = (float*)d_out;

  // 1. all laterals (flat + mlatb)
  lateral_all<<<2368, 256, 0, stream>>>(x3, x4, x5,
      lat3_w, lat3_s, lat3_b, lat4_w, lat4_s, lat4_b, lat5_w, lat5_s, lat5_b,
      mlat_w, mlat_s, mlat_b, flat, mlatb);
  // 2-3. mask feature branch
  conv3<<<512, 256, 0, stream>>>(mlatb, mhead_w, partial);
  mhead_fin<<<512, 256, 0, stream>>>(partial, mhead_s, mhead_b, mheadb);
  // 4-6. loc MLP (layers 1-3), layer 4 fused with final 256->1
  mlp_layer<0><<<1344, 256, 0, stream>>>(flat, buf,
      loc_hw, loc_hb, loc_lng, loc_lnb, nullptr, nullptr, nullptr, nullptr,
      nullptr, nullptr, nullptr, 0);
  for (int i = 1; i < 3; ++i)
    mlp_layer<0><<<1344, 256, 0, stream>>>(buf, buf,
        loc_hw + i*65536, loc_hb + i*256, loc_lng + i*256, loc_lnb + i*256,
        nullptr, nullptr, nullptr, nullptr, nullptr, nullptr, nullptr, 0);
  mlp_layer<1><<<1344, 256, 0, stream>>>(buf, nullptr,
      loc_hw + 3*65536, loc_hb + 3*256, loc_lng + 3*256, loc_lnb + 3*256,
      nullptr, nullptr, nullptr, nullptr, loc_fw, loc_fb, logits, 0);
  // 7. top-k + gather
  topk_gather<<<4, 256, 0, stream>>>(logits, flat, topi, gfeat, dout);
  // 8-11. cls+ker MLPs merged (rows 0-399 cls, 400-799 ker)
  mlp_layer<2><<<50, 256, 0, stream>>>(gfeat, h2,
      cls_hw, cls_hb, cls_lng, cls_lnb, ker_hw, ker_hb, ker_lng, ker_lnb,
      nullptr, nullptr, nullptr, -400);
  for (int i = 1; i < 4; ++i)
    mlp_layer<2><<<50, 256, 0, stream>>>(h2, h2,
        cls_hw + i*65536, cls_hb + i*256, cls_lng + i*256, cls_lnb + i*256,
        ker_hw + i*65536, ker_hb + i*256, ker_lng + i*256, ker_lnb + i*256,
        nullptr, nullptr, nullptr, 0);
  // 12. heads (cls argmax + ker params)
  heads<<<800, 256, 0, stream>>>(h2, cls_fw, cls_fb, ker_fw, ker_fb, dout, dynb);
  // 13. fused dynamic mask + sigmoid + bilinear 8x upsample
  mask_fused<<<1600, 256, 0, stream>>>(dynb, topi, mheadb, dout);
}